// Round 4
// baseline (84.821 us; speedup 1.0000x reference)
//
#include <hip/hip_runtime.h>
#include <math.h>

#define B_  4
#define N_  8192
#define M_  2048
#define O_  64
#define E_  64
#define F_  128
#define K_  7

__global__ __launch_bounds__(256, 2) void n3agg_kernel(
    const float* __restrict__ x, const float* __restrict__ xe,
    const float* __restrict__ ye, const float* __restrict__ log_temp,
    const int* __restrict__ I, float* __restrict__ out)
{
    __shared__ __align__(16) int   s_I[O_];
    __shared__ __align__(16) float s_ye[E_];
    __shared__ __align__(16) float s_W[O_ * K_];
    __shared__ __align__(16) float s_x[O_ * F_];     // 32 KB
    __shared__ __align__(16) float s_acc[F_ * K_];   // 3.5 KB

    const int bid = blockIdx.x;          // = b*M_ + m
    const int b   = bid >> 11;           // / M_ (2048)
    const int tid = threadIdx.x;

    // Phase 0: indices + ye row
    if (tid < O_) {
        s_I[tid] = I[(size_t)bid * O_ + tid];
    } else if (tid < O_ + E_) {
        s_ye[tid - O_] = ye[(size_t)bid * E_ + (tid - O_)];
    }
    __syncthreads();

    if (tid >= 64) {
        // Waves 1-3: prefetch the 64 gathered x-rows into LDS
        const int t = tid - 64;                    // 0..191
        for (int u = t; u < O_ * 32; u += 192) {   // 2048 float4 units
            const int row = u >> 5;
            const int off = u & 31;
            const int idx = s_I[row];
            float4 v = *(const float4*)(x + ((size_t)b * N_ + idx) * F_ + off * 4);
            *((float4*)(s_x + row * F_ + off * 4)) = v;
        }
    } else {
        // Wave 0, lane = o.
        // Distance in numpy AVX512 npyv-pairwise association:
        //   S[l] = (d2[l] + d2[l+16]) + (d2[l+32] + d2[l+48]),  l = 0..15
        //   then halving tree over l: distances 8, 4, 2, 1.
        const int lane = tid;
        const int idx = s_I[lane];
        const float4* xr4 = (const float4*)(xe + ((size_t)b * N_ + idx) * E_);
        const float4* ye4 = (const float4*)s_ye;
        float S[16];
        #pragma unroll
        for (int q = 0; q < 4; ++q) {
            float4 xa = xr4[q],      ya = ye4[q];
            float4 xb = xr4[q + 4],  yb = ye4[q + 4];
            float4 xc = xr4[q + 8],  yc = ye4[q + 8];
            float4 xd = xr4[q + 12], yd = ye4[q + 12];
            float da, db, dc, dd;

            da = __fsub_rn(xa.x, ya.x); db = __fsub_rn(xb.x, yb.x);
            dc = __fsub_rn(xc.x, yc.x); dd = __fsub_rn(xd.x, yd.x);
            S[4*q+0] = __fadd_rn(__fadd_rn(__fmul_rn(da,da), __fmul_rn(db,db)),
                                 __fadd_rn(__fmul_rn(dc,dc), __fmul_rn(dd,dd)));

            da = __fsub_rn(xa.y, ya.y); db = __fsub_rn(xb.y, yb.y);
            dc = __fsub_rn(xc.y, yc.y); dd = __fsub_rn(xd.y, yd.y);
            S[4*q+1] = __fadd_rn(__fadd_rn(__fmul_rn(da,da), __fmul_rn(db,db)),
                                 __fadd_rn(__fmul_rn(dc,dc), __fmul_rn(dd,dd)));

            da = __fsub_rn(xa.z, ya.z); db = __fsub_rn(xb.z, yb.z);
            dc = __fsub_rn(xc.z, yc.z); dd = __fsub_rn(xd.z, yd.z);
            S[4*q+2] = __fadd_rn(__fadd_rn(__fmul_rn(da,da), __fmul_rn(db,db)),
                                 __fadd_rn(__fmul_rn(dc,dc), __fmul_rn(dd,dd)));

            da = __fsub_rn(xa.w, ya.w); db = __fsub_rn(xb.w, yb.w);
            dc = __fsub_rn(xc.w, yc.w); dd = __fsub_rn(xd.w, yd.w);
            S[4*q+3] = __fadd_rn(__fadd_rn(__fmul_rn(da,da), __fmul_rn(db,db)),
                                 __fadd_rn(__fmul_rn(dc,dc), __fmul_rn(dd,dd)));
        }
        // halving tree (l, l+8), (l, l+4), (l, l+2), (l, l+1)
        float t8[8], t4[4], t2[2], res;
        #pragma unroll
        for (int l = 0; l < 8; ++l) t8[l] = __fadd_rn(S[l], S[l + 8]);
        #pragma unroll
        for (int l = 0; l < 4; ++l) t4[l] = __fadd_rn(t8[l], t8[l + 4]);
        t2[0] = __fadd_rn(t4[0], t4[2]);
        t2[1] = __fadd_rn(t4[1], t4[3]);
        res   = __fadd_rn(t2[0], t2[1]);

        const float temp = expf(log_temp[0]);      // exp(0) = 1.0f exactly
        float logit = __fdiv_rn(-res, temp);

        #pragma unroll
        for (int k = 0; k < K_; ++k) {
            // max: exact, order-independent
            float mx = logit;
            #pragma unroll
            for (int d = 1; d < 64; d <<= 1) mx = fmaxf(mx, __shfl_xor(mx, d));
            float sh = __fsub_rn(logit, mx);
            float ex = expf(sh);
            // sum(exp) in AVX512 npyv-pairwise association (bitwise via
            // commutativity of f32 add): xor16, xor32, then tree 8,4,2,1
            float t = __fadd_rn(ex, __shfl_xor(ex, 16));
            t = __fadd_rn(t, __shfl_xor(t, 32));
            t = __fadd_rn(t, __shfl_xor(t, 8));
            t = __fadd_rn(t, __shfl_xor(t, 4));
            t = __fadd_rn(t, __shfl_xor(t, 2));
            t = __fadd_rn(t, __shfl_xor(t, 1));
            const float sm = t;

            float w = __fsub_rn(sh, logf(sm));
            s_W[lane * K_ + k] = expf(w);

            // log1mexp, f32 semantics incl. f32-promoted LOG_HALF compare
            float lm;
            if (w < -0.69314718055994530942f) {
                lm = log1pf(-expf(w));
            } else {
                lm = logf(__fadd_rn(-expm1f(w), 1e-7f));
            }
            logit = __fadd_rn(logit, lm);
        }
    }
    __syncthreads();

    // Phase 3: z[f,k] = sum_o W[o,k] * x_g[o,f] (benign reduction, fma ok)
    {
        const int g = tid >> 7;       // 0 or 1
        const int f = tid & 127;
        float acc[K_];
        #pragma unroll
        for (int k = 0; k < K_; ++k) acc[k] = 0.f;
        const int o0 = g * 32;
        #pragma unroll 4
        for (int o = o0; o < o0 + 32; ++o) {
            const float xv = s_x[o * F_ + f];
            #pragma unroll
            for (int k = 0; k < K_; ++k)
                acc[k] = fmaf(s_W[o * K_ + k], xv, acc[k]);
        }
        if (g == 1) {
            #pragma unroll
            for (int k = 0; k < K_; ++k) s_acc[f * K_ + k] = acc[k];
        }
        __syncthreads();
        if (g == 0) {
            const size_t base = ((size_t)bid * F_ + f) * K_;
            #pragma unroll
            for (int k = 0; k < K_; ++k)
                out[base + k] = acc[k] + s_acc[f * K_ + k];
        }
    }
}

extern "C" void kernel_launch(void* const* d_in, const int* in_sizes, int n_in,
                              void* d_out, int out_size, void* d_ws, size_t ws_size,
                              hipStream_t stream) {
    const float* x        = (const float*)d_in[0];
    const float* xe       = (const float*)d_in[1];
    const float* ye       = (const float*)d_in[2];
    const float* log_temp = (const float*)d_in[3];
    const int*   I        = (const int*)d_in[4];
    float* out = (float*)d_out;

    dim3 grid(B_ * M_);
    dim3 block(256);
    hipLaunchKernelGGL(n3agg_kernel, grid, block, 0, stream,
                       x, xe, ye, log_temp, I, out);
}

// Round 5
// 65.054 us; speedup vs baseline: 1.3039x; 1.3039x over previous
//
#include <hip/hip_runtime.h>
#include <math.h>

#define B_  4
#define N_  8192
#define M_  2048
#define O_  64
#define E_  64
#define F_  128
#define K_  7

__global__ __launch_bounds__(256, 6) void n3agg_kernel(
    const float* __restrict__ x, const float* __restrict__ xe,
    const float* __restrict__ ye, const float* __restrict__ log_temp,
    const int* __restrict__ I, float* __restrict__ out)
{
    // Per-wave private LDS regions; no cross-wave communication, no barriers.
    __shared__ __align__(16) int   s_I[4][O_];
    __shared__ __align__(16) float s_ye[4][E_];
    __shared__ __align__(16) float s_W[4][K_][O_];

    const int tid  = threadIdx.x;
    const int w    = tid >> 6;
    const int lane = tid & 63;
    const int bid  = blockIdx.x * 4 + w;     // = b*M_ + m
    const int b    = bid >> 11;               // / 2048

    // Coalesced load of this wave's I row and ye row into its LDS region.
    const int my_idx = I[(size_t)bid * O_ + lane];
    s_I[w][lane]  = my_idx;
    s_ye[w][lane] = ye[(size_t)bid * E_ + lane];
    // (LDS ops within a wave complete in order; compiler inserts lgkmcnt.)

    // ---- Distance, numpy-AVX512 pairwise association (bit-exact, no fma) ----
    //   S[l] = (d2[l] + d2[l+16]) + (d2[l+32] + d2[l+48]), l = 0..15
    //   then halving tree over l: distances 8, 4, 2, 1.
    const float4* xr4 = (const float4*)(xe + ((size_t)b * N_ + my_idx) * E_);
    const float4* ye4 = (const float4*)(&s_ye[w][0]);
    float S[16];
    #pragma unroll
    for (int q = 0; q < 4; ++q) {
        float4 xa = xr4[q],      ya = ye4[q];
        float4 xb = xr4[q + 4],  yb = ye4[q + 4];
        float4 xc = xr4[q + 8],  yc = ye4[q + 8];
        float4 xd = xr4[q + 12], yd = ye4[q + 12];
        float da, db, dc, dd;

        da = __fsub_rn(xa.x, ya.x); db = __fsub_rn(xb.x, yb.x);
        dc = __fsub_rn(xc.x, yc.x); dd = __fsub_rn(xd.x, yd.x);
        S[4*q+0] = __fadd_rn(__fadd_rn(__fmul_rn(da,da), __fmul_rn(db,db)),
                             __fadd_rn(__fmul_rn(dc,dc), __fmul_rn(dd,dd)));

        da = __fsub_rn(xa.y, ya.y); db = __fsub_rn(xb.y, yb.y);
        dc = __fsub_rn(xc.y, yc.y); dd = __fsub_rn(xd.y, yd.y);
        S[4*q+1] = __fadd_rn(__fadd_rn(__fmul_rn(da,da), __fmul_rn(db,db)),
                             __fadd_rn(__fmul_rn(dc,dc), __fmul_rn(dd,dd)));

        da = __fsub_rn(xa.z, ya.z); db = __fsub_rn(xb.z, yb.z);
        dc = __fsub_rn(xc.z, yc.z); dd = __fsub_rn(xd.z, yd.z);
        S[4*q+2] = __fadd_rn(__fadd_rn(__fmul_rn(da,da), __fmul_rn(db,db)),
                             __fadd_rn(__fmul_rn(dc,dc), __fmul_rn(dd,dd)));

        da = __fsub_rn(xa.w, ya.w); db = __fsub_rn(xb.w, yb.w);
        dc = __fsub_rn(xc.w, yc.w); dd = __fsub_rn(xd.w, yd.w);
        S[4*q+3] = __fadd_rn(__fadd_rn(__fmul_rn(da,da), __fmul_rn(db,db)),
                             __fadd_rn(__fmul_rn(dc,dc), __fmul_rn(dd,dd)));
    }
    float t8[8], t4[4], t2[2], res;
    #pragma unroll
    for (int l = 0; l < 8; ++l) t8[l] = __fadd_rn(S[l], S[l + 8]);
    #pragma unroll
    for (int l = 0; l < 4; ++l) t4[l] = __fadd_rn(t8[l], t8[l + 4]);
    t2[0] = __fadd_rn(t4[0], t4[2]);
    t2[1] = __fadd_rn(t4[1], t4[3]);
    res   = __fadd_rn(t2[0], t2[1]);

    const float temp = expf(log_temp[0]);      // exp(0) = 1.0f exactly
    float logit = __fdiv_rn(-res, temp);

    // ---- K-step relaxed top-k, exact f32 semantics ----
    #pragma unroll
    for (int k = 0; k < K_; ++k) {
        float mx = logit;
        #pragma unroll
        for (int d = 1; d < 64; d <<= 1) mx = fmaxf(mx, __shfl_xor(mx, d));
        float sh = __fsub_rn(logit, mx);
        float ex = expf(sh);
        // sum(exp) in AVX512 npyv-pairwise association: xor16, xor32, 8,4,2,1
        float t = __fadd_rn(ex, __shfl_xor(ex, 16));
        t = __fadd_rn(t, __shfl_xor(t, 32));
        t = __fadd_rn(t, __shfl_xor(t, 8));
        t = __fadd_rn(t, __shfl_xor(t, 4));
        t = __fadd_rn(t, __shfl_xor(t, 2));
        t = __fadd_rn(t, __shfl_xor(t, 1));
        const float sm = t;

        float wv = __fsub_rn(sh, logf(sm));
        s_W[w][k][lane] = expf(wv);

        float lm;
        if (wv < -0.69314718055994530942f) {
            lm = log1pf(-expf(wv));
        } else {
            lm = logf(__fadd_rn(-expm1f(wv), 1e-7f));
        }
        logit = __fadd_rn(logit, lm);
    }

    // ---- Aggregation: lane owns f = {2*lane, 2*lane+1} ----
    // Direct coalesced global reads of x rows (no LDS staging; L2-served).
    float acc0[K_], acc1[K_];
    #pragma unroll
    for (int k = 0; k < K_; ++k) { acc0[k] = 0.f; acc1[k] = 0.f; }
    const float* xbase = x + (size_t)b * N_ * F_ + 2 * lane;
    #pragma unroll 4
    for (int o = 0; o < O_; ++o) {
        const int idx = s_I[w][o];                       // LDS broadcast
        const float2 xv = *(const float2*)(xbase + (size_t)idx * F_);
        #pragma unroll
        for (int k = 0; k < K_; ++k) {
            const float wk = s_W[w][k][o];               // LDS broadcast
            acc0[k] = fmaf(wk, xv.x, acc0[k]);
            acc1[k] = fmaf(wk, xv.y, acc1[k]);
        }
    }
    // Store: lane writes 14 consecutive floats -> wave covers 3584B contiguous.
    float* op = out + (size_t)bid * F_ * K_ + lane * 2 * K_;
    #pragma unroll
    for (int k = 0; k < K_; ++k) op[k] = acc0[k];
    #pragma unroll
    for (int k = 0; k < K_; ++k) op[K_ + k] = acc1[k];
}

extern "C" void kernel_launch(void* const* d_in, const int* in_sizes, int n_in,
                              void* d_out, int out_size, void* d_ws, size_t ws_size,
                              hipStream_t stream) {
    const float* x        = (const float*)d_in[0];
    const float* xe       = (const float*)d_in[1];
    const float* ye       = (const float*)d_in[2];
    const float* log_temp = (const float*)d_in[3];
    const int*   I        = (const int*)d_in[4];
    float* out = (float*)d_out;

    dim3 grid((B_ * M_) / 4);   // 4 independent (b,m) waves per block
    dim3 block(256);
    hipLaunchKernelGGL(n3agg_kernel, grid, block, 0, stream,
                       x, xe, ye, log_temp, I, out);
}

// Round 6
// 64.603 us; speedup vs baseline: 1.3130x; 1.0070x over previous
//
#include <hip/hip_runtime.h>
#include <math.h>

#define B_  4
#define N_  8192
#define M_  2048
#define O_  64
#define E_  64
#define F_  128
#define K_  7

__global__ __launch_bounds__(128, 6) void n3agg_kernel(
    const float* __restrict__ x, const float* __restrict__ xe,
    const float* __restrict__ ye, const float* __restrict__ log_temp,
    const int* __restrict__ I, float* __restrict__ out)
{
    // Per-wave private LDS; no cross-wave communication, no barriers.
    __shared__ __align__(16) int   s_I[2][O_];
    __shared__ __align__(16) float s_ye[2][E_];
    __shared__ __align__(16) float s_W[2][O_][8];   // k padded 7->8 for b128 reads

    const int tid  = threadIdx.x;
    const int w    = tid >> 6;
    const int lane = tid & 63;
    const int bid  = blockIdx.x * 2 + w;     // = b*M_ + m
    const int b    = bid >> 11;              // / 2048

    // Wave-coalesced load of I row and ye row into this wave's LDS region.
    const int my_idx = I[(size_t)bid * O_ + lane];
    s_I[w][lane]  = my_idx;
    s_ye[w][lane] = ye[(size_t)bid * E_ + lane];

    // ---- Distance, numpy-AVX512 pairwise association (bit-exact, no fma) ----
    const float4* xr4 = (const float4*)(xe + ((size_t)b * N_ + my_idx) * E_);
    const float4* ye4 = (const float4*)(&s_ye[w][0]);
    float S[16];
    #pragma unroll
    for (int q = 0; q < 4; ++q) {
        float4 xa = xr4[q],      ya = ye4[q];
        float4 xb = xr4[q + 4],  yb = ye4[q + 4];
        float4 xc = xr4[q + 8],  yc = ye4[q + 8];
        float4 xd = xr4[q + 12], yd = ye4[q + 12];
        float da, db, dc, dd;

        da = __fsub_rn(xa.x, ya.x); db = __fsub_rn(xb.x, yb.x);
        dc = __fsub_rn(xc.x, yc.x); dd = __fsub_rn(xd.x, yd.x);
        S[4*q+0] = __fadd_rn(__fadd_rn(__fmul_rn(da,da), __fmul_rn(db,db)),
                             __fadd_rn(__fmul_rn(dc,dc), __fmul_rn(dd,dd)));

        da = __fsub_rn(xa.y, ya.y); db = __fsub_rn(xb.y, yb.y);
        dc = __fsub_rn(xc.y, yc.y); dd = __fsub_rn(xd.y, yd.y);
        S[4*q+1] = __fadd_rn(__fadd_rn(__fmul_rn(da,da), __fmul_rn(db,db)),
                             __fadd_rn(__fmul_rn(dc,dc), __fmul_rn(dd,dd)));

        da = __fsub_rn(xa.z, ya.z); db = __fsub_rn(xb.z, yb.z);
        dc = __fsub_rn(xc.z, yc.z); dd = __fsub_rn(xd.z, yd.z);
        S[4*q+2] = __fadd_rn(__fadd_rn(__fmul_rn(da,da), __fmul_rn(db,db)),
                             __fadd_rn(__fmul_rn(dc,dc), __fmul_rn(dd,dd)));

        da = __fsub_rn(xa.w, ya.w); db = __fsub_rn(xb.w, yb.w);
        dc = __fsub_rn(xc.w, yc.w); dd = __fsub_rn(xd.w, yd.w);
        S[4*q+3] = __fadd_rn(__fadd_rn(__fmul_rn(da,da), __fmul_rn(db,db)),
                             __fadd_rn(__fmul_rn(dc,dc), __fmul_rn(dd,dd)));
    }
    float t8[8], t4[4], t2[2], res;
    #pragma unroll
    for (int l = 0; l < 8; ++l) t8[l] = __fadd_rn(S[l], S[l + 8]);
    #pragma unroll
    for (int l = 0; l < 4; ++l) t4[l] = __fadd_rn(t8[l], t8[l + 4]);
    t2[0] = __fadd_rn(t4[0], t4[2]);
    t2[1] = __fadd_rn(t4[1], t4[3]);
    res   = __fadd_rn(t2[0], t2[1]);

    const float temp = expf(log_temp[0]);      // exp(0) = 1.0f exactly
    float logit = __fdiv_rn(-res, temp);

    // ---- K-step relaxed top-k, exact f32 semantics; W kept in registers ----
    float wreg[K_];
    #pragma unroll
    for (int k = 0; k < K_; ++k) {
        float mx = logit;
        #pragma unroll
        for (int d = 1; d < 64; d <<= 1) mx = fmaxf(mx, __shfl_xor(mx, d));
        float sh = __fsub_rn(logit, mx);
        float ex = expf(sh);
        // sum(exp) in AVX512 npyv-pairwise association: xor16, xor32, 8,4,2,1
        float t = __fadd_rn(ex, __shfl_xor(ex, 16));
        t = __fadd_rn(t, __shfl_xor(t, 32));
        t = __fadd_rn(t, __shfl_xor(t, 8));
        t = __fadd_rn(t, __shfl_xor(t, 4));
        t = __fadd_rn(t, __shfl_xor(t, 2));
        t = __fadd_rn(t, __shfl_xor(t, 1));
        const float sm = t;

        float wv = __fsub_rn(sh, logf(sm));
        wreg[k] = expf(wv);

        float lm;
        if (wv < -0.69314718055994530942f) {
            lm = log1pf(-expf(wv));
        } else {
            lm = logf(__fadd_rn(-expm1f(wv), 1e-7f));
        }
        logit = __fadd_rn(logit, lm);
    }
    // One packed write of this lane's W row (b128 + b64 + b32).
    {
        float* wp = &s_W[w][lane][0];
        *(float4*)wp       = make_float4(wreg[0], wreg[1], wreg[2], wreg[3]);
        *(float2*)(wp + 4) = make_float2(wreg[4], wreg[5]);
        wp[6] = wreg[6];
    }

    // ---- Aggregation: o-parity split; lane owns f-quad 4*(lane&31) ----
    const int h  = lane >> 5;                  // 0: even o, 1: odd o
    const int fl = lane & 31;                  // f-quad index
    float acc[4][K_];
    #pragma unroll
    for (int q = 0; q < 4; ++q)
        #pragma unroll
        for (int k = 0; k < K_; ++k) acc[q][k] = 0.f;

    const float* xb = x + (size_t)b * N_ * F_ + 4 * fl;
    #pragma unroll 2
    for (int t = 0; t < 32; ++t) {
        const int o = 2 * t + h;
        const int idx = s_I[w][o];                       // 2-addr broadcast
        const float4 xv = *(const float4*)(xb + (size_t)idx * F_);
        const float* wrow = &s_W[w][o][0];
        const float4 wa = *(const float4*)(wrow);        // W[o][0..3]
        const float4 wb = *(const float4*)(wrow + 4);    // W[o][4..6] (+pad)
        const float wk[K_] = {wa.x, wa.y, wa.z, wa.w, wb.x, wb.y, wb.z};
        #pragma unroll
        for (int k = 0; k < K_; ++k) {
            acc[0][k] = fmaf(wk[k], xv.x, acc[0][k]);
            acc[1][k] = fmaf(wk[k], xv.y, acc[1][k]);
            acc[2][k] = fmaf(wk[k], xv.z, acc[2][k]);
            acc[3][k] = fmaf(wk[k], xv.w, acc[3][k]);
        }
    }
    // Combine even/odd halves: lanes 0..31 end with full sums.
    #pragma unroll
    for (int q = 0; q < 4; ++q)
        #pragma unroll
        for (int k = 0; k < K_; ++k)
            acc[q][k] += __shfl_xor(acc[q][k], 32);

    if (lane < 32) {
        // Lane stores 28 contiguous floats (f=4*fl..4*fl+3, k-major inner).
        const float* af = &acc[0][0];
        float4* op4 = (float4*)(out + (size_t)bid * F_ * K_ + fl * 28);
        #pragma unroll
        for (int j = 0; j < 7; ++j)
            op4[j] = make_float4(af[4*j], af[4*j+1], af[4*j+2], af[4*j+3]);
    }
}

extern "C" void kernel_launch(void* const* d_in, const int* in_sizes, int n_in,
                              void* d_out, int out_size, void* d_ws, size_t ws_size,
                              hipStream_t stream) {
    const float* x        = (const float*)d_in[0];
    const float* xe       = (const float*)d_in[1];
    const float* ye       = (const float*)d_in[2];
    const float* log_temp = (const float*)d_in[3];
    const int*   I        = (const int*)d_in[4];
    float* out = (float*)d_out;

    dim3 grid((B_ * M_) / 2);   // 2 independent (b,m) waves per block
    dim3 block(128);
    hipLaunchKernelGGL(n3agg_kernel, grid, block, 0, stream,
                       x, xe, ye, log_temp, I, out);
}